// Round 3
// baseline (33839.227 us; speedup 1.0000x reference)
//
#include <hip/hip_runtime.h>

typedef unsigned short u16;
typedef unsigned int u32;
typedef _Float16 f16;
typedef __attribute__((ext_vector_type(8))) _Float16 f16x8;
typedef __attribute__((ext_vector_type(4))) float f32x4;

#define TT 512
#define DD 64
#define SC 2048.0f
#define ISC (1.0f / 2048.0f)

// Activation buffers (H1/H2/Z): f16 hi/lo-split pairs, MFMA-fragment layout:
// [mtile(16)][ks(32: 0-15 hi, 16-31 lo*2^11)][1KB frag]; frag elem
// (m=lane&15, k=quad*8+i) at quad*128 + m*8 + (k&7). Weight B-frags likewise
// split into H and L (L pre-scaled by 2^11; true value = H + L/2^11).
struct WS {
  f16 *PB1aH, *PB1aL, *PB1bH, *PB1bL, *PB1xH, *PB1xL;
  f16 *PB2aH, *PB2aL, *PB2bH, *PB2bL, *PBo;
  float *wz1, *wz2, *b1f, *b2f, *bof;
  f16 *H1[2], *H2[2], *Z[2];
  float *c1, *c2, *h2m;
  float *z1[2], *z2[2];
  int *flag;  // 1 = inputs are float32, 0 = inputs are bf16
};

__device__ __forceinline__ float bf2f(u16 u) { return __uint_as_float(((u32)u) << 16); }
__device__ __forceinline__ u16 f2bf(float f) {
  u32 u = __float_as_uint(f);
  u += 0x7fffu + ((u >> 16) & 1u);
  return (u16)(u >> 16);
}
// dtype-flexible scalar load of input element i
__device__ __forceinline__ float ldw(const void* p, size_t i, int f32) {
  return f32 ? ((const float*)p)[i] : bf2f(((const u16*)p)[i]);
}
__device__ __forceinline__ float sigm(float x) { return 1.0f / (1.0f + expf(-x)); }
__device__ __forceinline__ f16x8 ldf(const f16* p) { return *(const f16x8*)p; }

#define MFMA(a, b, c) __builtin_amdgcn_mfma_f32_16x16x32_f16(a, b, c, 0, 0, 0)

// ---------------- dtype detection ----------------
// bf16 N(0,1)/U(±.04) data: exponent byte in ~[0x66,0x82]; fp32 arrays read as
// u16 have uniform-random low halfwords -> ~40% land in the "insane" ranges.
__global__ void detect_kernel(const u16* __restrict__ x, int* __restrict__ flag)
{
  int tid = threadIdx.x;  // 64 threads
  int cnt = 0;
  for (int i = tid; i < 8192; i += 64) {
    int e = (x[i] >> 7) & 0xFF;
    cnt += (e >= 0xC0 || (e != 0 && e < 0x30)) ? 1 : 0;
  }
#pragma unroll
  for (int off = 32; off; off >>= 1) cnt += __shfl_down(cnt, off);
  if (tid == 0) *flag = (cnt > 100) ? 1 : 0;
}

// ---------------- prologue: weight packing ----------------
__device__ __forceinline__ void packGate(const void* __restrict__ U,
                                         f16* __restrict__ dstH, f16* __restrict__ dstL,
                                         int g, int KS, int F32) {
  int lane = g & 63;
  int rest = g >> 6;
  int t2 = rest & 1; rest >>= 1;
  int ks = rest % KS;
  int J  = rest / KS;
  int q = lane >> 4, n = lane & 15;
  int j = J * 8 + (n & 7);
  int c = (t2 * 2 + (n >> 3)) * 512 + j;
  int kb = ks * 32 + q * 8;
  f16 vh[8], vl[8];
#pragma unroll
  for (int i = 0; i < 8; ++i) {
    float v = ldw(U, (size_t)(kb + i) * 2049 + c, F32);
    f16 h = (f16)v;
    vh[i] = h;
    vl[i] = (f16)((v - (float)h) * SC);
  }
  *(f16x8*)(dstH + (size_t)g * 8) = *(f16x8*)vh;
  *(f16x8*)(dstL + (size_t)g * 8) = *(f16x8*)vl;
}

#define NPACK (4 * 131072 + 16384 + 8192 + 2112 + 2048 + 2049 + 2049 + 64)

__global__ __launch_bounds__(256) void pack_kernel(
    const void* __restrict__ U11_1, const void* __restrict__ U21_1,
    const void* __restrict__ W01_1, const void* __restrict__ bias1,
    const void* __restrict__ U11_2, const void* __restrict__ W01_2,
    const void* __restrict__ bias2, const void* __restrict__ l1W,
    const void* __restrict__ l1b, const void* __restrict__ l2W,
    const void* __restrict__ l2b, WS w)
{
  const int F32 = *w.flag;
  int gid = blockIdx.x * 256 + threadIdx.x;
  const int NG = 131072;
  if (gid < NG) { packGate(U11_1, w.PB1aH, w.PB1aL, gid, 16, F32); return; }
  gid -= NG;
  if (gid < NG) { packGate(U21_1, w.PB1bH, w.PB1bL, gid, 16, F32); return; }
  gid -= NG;
  if (gid < NG) { packGate(U11_2, w.PB2aH, w.PB2aL, gid, 16, F32); return; }
  gid -= NG;
  if (gid < NG) { packGate(W01_2, w.PB2bH, w.PB2bL, gid, 16, F32); return; }
  gid -= NG;
  if (gid < 16384) { packGate(W01_1, w.PB1xH, w.PB1xL, gid, 2, F32); return; }
  gid -= 16384;
  if (gid < 8192) {  // PBo (hi only): [w4][ks 0..31][lane][8]
    int lane = gid & 63;
    int rest = gid >> 6;
    int ks = rest & 31;
    int w4 = rest >> 5;
    int q = lane >> 4;
    int d = w4 * 16 + (lane & 15);
    int kb = ks * 32 + q * 8;
    f16 v[8];
#pragma unroll
    for (int i = 0; i < 8; ++i) {
      int k = kb + i;
      float s = (k < 512) ? ldw(l1W, (size_t)d * 512 + k, F32)
                          : ldw(l2W, (size_t)d * 512 + (k - 512), F32);
      v[i] = (f16)s;
    }
    *(f16x8*)(w.PBo + (size_t)gid * 8) = *(f16x8*)v;
    return;
  }
  gid -= 8192;
  if (gid < 2112) {  // z-column weights, cell1 (fp32 exact)
    int i = gid; float s;
    if (i < 512)       s = ldw(U11_1, (size_t)i * 2049 + 2048, F32);
    else if (i < 1024) s = ldw(U11_1, (size_t)(i - 512) * 2049 + 2048, F32);
    else if (i < 1536) s = ldw(U21_1, (size_t)(i - 1024) * 2049 + 2048, F32);
    else if (i < 2048) s = ldw(U21_1, (size_t)(i - 1536) * 2049 + 2048, F32);
    else               s = ldw(W01_1, (size_t)(i - 2048) * 2049 + 2048, F32);
    w.wz1[i] = s; return;
  }
  gid -= 2112;
  if (gid < 2048) {  // z-column weights, cell2
    int i = gid; float s;
    if (i < 512)       s = ldw(U11_2, (size_t)i * 2049 + 2048, F32);
    else if (i < 1024) s = ldw(U11_2, (size_t)(i - 512) * 2049 + 2048, F32);
    else if (i < 1536) s = ldw(W01_2, (size_t)(i - 1024) * 2049 + 2048, F32);
    else               s = ldw(W01_2, (size_t)(i - 1536) * 2049 + 2048, F32);
    w.wz2[i] = s; return;
  }
  gid -= 2048;
  if (gid < 2049) { w.b1f[gid] = ldw(bias1, gid, F32); return; }
  gid -= 2049;
  if (gid < 2049) { w.b2f[gid] = ldw(bias2, gid, F32); return; }
  gid -= 2049;
  if (gid < 64) { w.bof[gid] = ldw(l1b, gid, F32) + ldw(l2b, gid, F32); return; }
}

__global__ __launch_bounds__(256) void init_kernel(WS w)
{
  size_t id = (size_t)blockIdx.x * 256 + threadIdx.x;
  const size_t nw = 131072;  // u32 words per f16 state buffer
  if (id < 3 * nw) {
    u32* p = (id < nw) ? (u32*)w.H1[1] : (id < 2 * nw) ? (u32*)w.H2[1] : (u32*)w.Z[1];
    p[id % nw] = 0u;
    return;
  }
  id -= 3 * nw;
  const size_t nf = 131072;
  if (id < 3 * nf) {
    float* p = (id < nf) ? w.c1 : (id < 2 * nf) ? w.c2 : w.h2m;
    p[id % nf] = 0.0f;
    return;
  }
  id -= 3 * nf;
  if (id < 512) {
    ((id < 256) ? w.z1[1] : w.z2[1])[id & 255] = 0.0f;
  }
}

// ---------------- output tile: out[b,twrite,:] = h1@l1W^T + h2@l2W^T + bias ----
__device__ __forceinline__ void out_tile(const WS& w, void* __restrict__ out, int F32,
                                         int pq, int twrite, int ot, int wv, int lane)
{
  const f16* A1 = w.H1[pq] + (size_t)ot * 16384 + lane * 8;  // hi sections only
  const f16* A2 = w.H2[pq] + (size_t)ot * 16384 + lane * 8;
  const f16* Bo = w.PBo + (size_t)wv * 16384 + lane * 8;
  f32x4 acc = {0.f, 0.f, 0.f, 0.f};
#pragma unroll
  for (int k = 0; k < 16; ++k) acc = MFMA(ldf(A1 + k * 512), ldf(Bo + k * 512), acc);
#pragma unroll
  for (int k = 0; k < 16; ++k) acc = MFMA(ldf(A2 + k * 512), ldf(Bo + (16 + k) * 512), acc);
  const int q = lane >> 4;
  const int d = wv * 16 + (lane & 15);
  const float bias = w.bof[d];
#pragma unroll
  for (int r = 0; r < 4; ++r) {
    const int b = ot * 16 + q * 4 + r;
    const size_t idx = ((size_t)b * TT + twrite) * DD + d;
    const float val = acc[r] + bias;
    if (F32) ((float*)out)[idx] = val;
    else     ((u16*)out)[idx] = f2bf(val);
  }
}

// ---------------- step1: cell 1 (GEMM + gates + z1) + out_{t-1} ----------------
__global__ __launch_bounds__(256) void step1(const void* __restrict__ x,
                                             void* __restrict__ out, WS w, int t)
{
  const int F32 = *w.flag;
  const int pc = t & 1, pp = pc ^ 1;
  const int bid = blockIdx.x;
  const int tid = threadIdx.x;
  const int lane = tid & 63, wv = tid >> 6;

  if (bid < 256) {
    const int mt = bid >> 5, Jp = bid & 31;
    const int mhalf = wv & 1, cp = wv >> 1;
    const int J = Jp * 2 + cp;
    const int mtile = mt * 2 + mhalf;
    const int m0 = mtile * 16;
    const f16* A1 = w.H1[pp] + (size_t)mtile * 16384 + lane * 8;
    const f16* AZ = w.Z[pp]  + (size_t)mtile * 16384 + lane * 8;
    const f16* BaH = w.PB1aH + (size_t)J * 16384 + lane * 8;
    const f16* BaL = w.PB1aL + (size_t)J * 16384 + lane * 8;
    const f16* BbH = w.PB1bH + (size_t)J * 16384 + lane * 8;
    const f16* BbL = w.PB1bL + (size_t)J * 16384 + lane * 8;
    const f16* BxH = w.PB1xH + (size_t)J * 2048  + lane * 8;
    const f16* BxL = w.PB1xL + (size_t)J * 2048  + lane * 8;
    f32x4 hFI = {0.f,0.f,0.f,0.f}, lFI = {0.f,0.f,0.f,0.f};
    f32x4 hOG = {0.f,0.f,0.f,0.f}, lOG = {0.f,0.f,0.f,0.f};
#pragma unroll
    for (int k = 0; k < 16; ++k) {  // h1 @ U11_1, full hi/lo product (3 terms)
      f16x8 ah = ldf(A1 + k * 512);
      f16x8 al = ldf(A1 + (16 + k) * 512);
      f16x8 b0h = ldf(BaH + k * 1024), b0l = ldf(BaL + k * 1024);
      f16x8 b1h = ldf(BaH + k * 1024 + 512), b1l = ldf(BaL + k * 1024 + 512);
      hFI = MFMA(ah, b0h, hFI);
      lFI = MFMA(al, b0h, lFI); lFI = MFMA(ah, b0l, lFI);
      hOG = MFMA(ah, b1h, hOG);
      lOG = MFMA(al, b1h, lOG); lOG = MFMA(ah, b1l, lOG);
    }
#pragma unroll
    for (int k = 0; k < 16; ++k) {  // (z1_prev * h2) @ U21_1
      f16x8 ah = ldf(AZ + k * 512);
      f16x8 al = ldf(AZ + (16 + k) * 512);
      f16x8 b0h = ldf(BbH + k * 1024), b0l = ldf(BbL + k * 1024);
      f16x8 b1h = ldf(BbH + k * 1024 + 512), b1l = ldf(BbL + k * 1024 + 512);
      hFI = MFMA(ah, b0h, hFI);
      lFI = MFMA(al, b0h, lFI); lFI = MFMA(ah, b0l, lFI);
      hOG = MFMA(ah, b1h, hOG);
      lOG = MFMA(al, b1h, lOG); lOG = MFMA(ah, b1l, lOG);
    }
    {  // x_t @ W01_1 with hi/lo split of x
      const int row = m0 + (lane & 15);
      const int qq = lane >> 4;
#pragma unroll
      for (int kx = 0; kx < 2; ++kx) {
        const int d = kx * 32 + qq * 8;
        const size_t xoff = ((size_t)row * TT + t) * DD + d;
        float xv[8];
        if (F32) {
          const float* px = (const float*)x + xoff;
          float4 r0 = *(const float4*)px;
          float4 r1 = *(const float4*)(px + 4);
          xv[0]=r0.x; xv[1]=r0.y; xv[2]=r0.z; xv[3]=r0.w;
          xv[4]=r1.x; xv[5]=r1.y; xv[6]=r1.z; xv[7]=r1.w;
        } else {
          const u16* px = (const u16*)x + xoff;
          uint4 raw = *(const uint4*)px;
          u32 rr4[4] = {raw.x, raw.y, raw.z, raw.w};
#pragma unroll
          for (int i = 0; i < 4; ++i) {
            xv[2*i]   = bf2f((u16)(rr4[i] & 0xffffu));
            xv[2*i+1] = bf2f((u16)(rr4[i] >> 16));
          }
        }
        f16x8 axh, axl;
#pragma unroll
        for (int i = 0; i < 8; ++i) {
          f16 h = (f16)xv[i];
          axh[i] = h;
          axl[i] = (f16)((xv[i] - (float)h) * SC);
        }
        f16x8 b0h = ldf(BxH + kx * 1024), b0l = ldf(BxL + kx * 1024);
        f16x8 b1h = ldf(BxH + kx * 1024 + 512), b1l = ldf(BxL + kx * 1024 + 512);
        hFI = MFMA(axh, b0h, hFI);
        lFI = MFMA(axl, b0h, lFI); lFI = MFMA(axh, b0l, lFI);
        hOG = MFMA(axh, b1h, hOG);
        lOG = MFMA(axl, b1h, lOG); lOG = MFMA(axh, b1l, lOG);
      }
    }
    float accFI[4], accOG[4];
#pragma unroll
    for (int r = 0; r < 4; ++r) {
      accFI[r] = hFI[r] + lFI[r] * ISC;
      accOG[r] = hOG[r] + lOG[r] * ISC;
    }
    // fused cell-1 epilogue (z = z1_prev, z_bottom = 1 -> h = o*tanh(c))
    const int q = lane >> 4;
    const int jcol = J * 8 + (lane & 7);
    const bool ilane = (lane & 8) != 0;
    float oFI[4], oOG[4];
#pragma unroll
    for (int r = 0; r < 4; ++r) {
      oFI[r] = __shfl_xor(accFI[r], 8);
      oOG[r] = __shfl_xor(accOG[r], 8);
    }
    const float bf_ = w.b1f[jcol], bi_ = w.b1f[512 + jcol];
    const float bo_ = w.b1f[1024 + jcol], bg_ = w.b1f[1536 + jcol];
    const int r0 = ilane ? 2 : 0;
#pragma unroll
    for (int rr = 0; rr < 2; ++rr) {
      const int r = r0 + rr;
      const int b = m0 + q * 4 + r;
      const float sf = (ilane ? oFI[r] : accFI[r]) + bf_;
      const float si = (ilane ? accFI[r] : oFI[r]) + bi_;
      const float so = (ilane ? oOG[r] : accOG[r]) + bo_;
      const float sg = (ilane ? accOG[r] : oOG[r]) + bg_;
      const float f = sigm(sf), i_ = sigm(si), o = sigm(so), g = tanhf(sg);
      const int idx = b * 512 + jcol;
      const float cold = w.c1[idx];
      const float z1p = w.z1[pp][b];
      const float ig = i_ * g;
      const float cn = (z1p != 0.0f) ? ig : (f * cold + ig);
      const float hn = o * tanhf(cn);
      w.c1[idx] = cn;
      const f16 hi = (f16)hn;
      const f16 lo = (f16)((hn - (float)hi) * SC);
      const size_t off = (size_t)(b >> 4) * 16384 + (size_t)(jcol >> 5) * 512
                       + ((jcol >> 3) & 3) * 128 + (b & 15) * 8 + (jcol & 7);
      w.H1[pc][off] = hi;
      w.H1[pc][off + 8192] = lo;
    }
  } else if (bid == 256) {
    // z1 logit per batch row, fp64 accumulation for threshold decisions
    const int b = tid;
    const f16* pa = w.H1[pp] + (size_t)(b >> 4) * 16384 + (b & 15) * 8;
    const f16* pz = w.Z[pp]  + (size_t)(b >> 4) * 16384 + (b & 15) * 8;
    double acc[4] = {0.0, 0.0, 0.0, 0.0};
#pragma unroll 4
    for (int ks = 0; ks < 16; ++ks) {
#pragma unroll
      for (int qq = 0; qq < 4; ++qq) {
        const int j = ks * 32 + qq * 8;
        f16x8 h8 = ldf(pa + ks * 512 + qq * 128);
        f16x8 l8 = ldf(pa + ks * 512 + qq * 128 + 8192);
#pragma unroll
        for (int i = 0; i < 8; ++i) {
          double h = (double)(float)h8[i] + (double)(float)l8[i] * (1.0 / 2048.0);
          acc[i & 3] += h * (double)w.wz1[j + i];
        }
        f16x8 h8z = ldf(pz + ks * 512 + qq * 128);
        f16x8 l8z = ldf(pz + ks * 512 + qq * 128 + 8192);
#pragma unroll
        for (int i = 0; i < 8; ++i) {
          double h = (double)(float)h8z[i] + (double)(float)l8z[i] * (1.0 / 2048.0);
          acc[i & 3] += h * (double)w.wz1[1024 + j + i];
        }
      }
    }
    const size_t xoff = (size_t)b * TT * DD + (size_t)t * DD;
#pragma unroll 8
    for (int d = 0; d < 64; ++d) {
      float xv = ldw(x, xoff + d, F32);
      acc[d & 3] += (double)xv * (double)w.wz1[2048 + d];
    }
    double s = ((acc[0] + acc[1]) + (acc[2] + acc[3])) + (double)w.b1f[2048];
    float sz = (float)s;
    float zh = (sz + 1.0f) * 0.5f;  // round-half-even(zh) == (zh > 0.5)
    w.z1[pc][b] = (zh > 0.5f) ? 1.0f : 0.0f;
  } else {
    if (t == 0) return;  // out_{t-1} piggyback
    out_tile(w, out, F32, pp, t - 1, bid - 257, wv, lane);
  }
}

// ---------------- step2: cell 2 (GEMM + gates + z2) ----------------
__global__ __launch_bounds__(256) void step2(WS w, int t)
{
  const int pc = t & 1, pp = pc ^ 1;
  const int bid = blockIdx.x;
  const int tid = threadIdx.x;
  const int lane = tid & 63, wv = tid >> 6;
  if (bid < 256) {
    const int mt = bid >> 5, Jp = bid & 31;
    const int mhalf = wv & 1, cp = wv >> 1;
    const int J = Jp * 2 + cp;
    const int mtile = mt * 2 + mhalf;
    const int m0 = mtile * 16;
    const f16* Aa = w.H2[pp] + (size_t)mtile * 16384 + lane * 8;  // h2_prev
    const f16* Ab = w.H1[pc] + (size_t)mtile * 16384 + lane * 8;  // h1_new
    const f16* BaH = w.PB2aH + (size_t)J * 16384 + lane * 8;
    const f16* BaL = w.PB2aL + (size_t)J * 16384 + lane * 8;
    const f16* BbH = w.PB2bH + (size_t)J * 16384 + lane * 8;
    const f16* BbL = w.PB2bL + (size_t)J * 16384 + lane * 8;
    f32x4 aFIh = {0.f,0.f,0.f,0.f}, aFIl = {0.f,0.f,0.f,0.f};
    f32x4 aOGh = {0.f,0.f,0.f,0.f}, aOGl = {0.f,0.f,0.f,0.f};
    f32x4 bFIh = {0.f,0.f,0.f,0.f}, bFIl = {0.f,0.f,0.f,0.f};
    f32x4 bOGh = {0.f,0.f,0.f,0.f}, bOGl = {0.f,0.f,0.f,0.f};
#pragma unroll
    for (int k = 0; k < 16; ++k) {  // h2 @ U11_2
      f16x8 ah = ldf(Aa + k * 512);
      f16x8 al = ldf(Aa + (16 + k) * 512);
      f16x8 b0h = ldf(BaH + k * 1024), b0l = ldf(BaL + k * 1024);
      f16x8 b1h = ldf(BaH + k * 1024 + 512), b1l = ldf(BaL + k * 1024 + 512);
      aFIh = MFMA(ah, b0h, aFIh);
      aFIl = MFMA(al, b0h, aFIl); aFIl = MFMA(ah, b0l, aFIl);
      aOGh = MFMA(ah, b1h, aOGh);
      aOGl = MFMA(al, b1h, aOGl); aOGl = MFMA(ah, b1l, aOGl);
    }
#pragma unroll
    for (int k = 0; k < 16; ++k) {  // h1_new @ W01_2 (z1-scaled in epilogue)
      f16x8 ah = ldf(Ab + k * 512);
      f16x8 al = ldf(Ab + (16 + k) * 512);
      f16x8 b0h = ldf(BbH + k * 1024), b0l = ldf(BbL + k * 1024);
      f16x8 b1h = ldf(BbH + k * 1024 + 512), b1l = ldf(BbL + k * 1024 + 512);
      bFIh = MFMA(ah, b0h, bFIh);
      bFIl = MFMA(al, b0h, bFIl); bFIl = MFMA(ah, b0l, bFIl);
      bOGh = MFMA(ah, b1h, bOGh);
      bOGl = MFMA(al, b1h, bOGl); bOGl = MFMA(ah, b1l, bOGl);
    }
    const int q = lane >> 4;
    const int jcol = J * 8 + (lane & 7);
    const bool ilane = (lane & 8) != 0;
    float z1v[4], z2v[4], cFI[4], cOG[4];
#pragma unroll
    for (int r = 0; r < 4; ++r) {
      const int b = m0 + q * 4 + r;
      z1v[r] = w.z1[pc][b];
      z2v[r] = w.z2[pp][b];
      const float av = aFIh[r] + aFIl[r] * ISC;
      const float bv = bFIh[r] + bFIl[r] * ISC;
      const float av2 = aOGh[r] + aOGl[r] * ISC;
      const float bv2 = bOGh[r] + bOGl[r] * ISC;
      cFI[r] = av + z1v[r] * bv;
      cOG[r] = av2 + z1v[r] * bv2;
    }
    float oFI[4], oOG[4];
#pragma unroll
    for (int r = 0; r < 4; ++r) {
      oFI[r] = __shfl_xor(cFI[r], 8);
      oOG[r] = __shfl_xor(cOG[r], 8);
    }
    const float bf_ = w.b2f[jcol], bi_ = w.b2f[512 + jcol];
    const float bo_ = w.b2f[1024 + jcol], bg_ = w.b2f[1536 + jcol];
    const int r0 = ilane ? 2 : 0;
#pragma unroll
    for (int rr = 0; rr < 2; ++rr) {
      const int r = r0 + rr;
      const int b = m0 + q * 4 + r;
      const float sf = (ilane ? oFI[r] : cFI[r]) + bf_;
      const float si = (ilane ? cFI[r] : oFI[r]) + bi_;
      const float so = (ilane ? oOG[r] : cOG[r]) + bo_;
      const float sg = (ilane ? cOG[r] : oOG[r]) + bg_;
      const float f = sigm(sf), i_ = sigm(si), o = sigm(so), g = tanhf(sg);
      const int idx = b * 512 + jcol;
      const float cold = w.c2[idx];
      const float h2old = w.h2m[idx];
      const float ig = i_ * g;
      const bool zz = (z2v[r] != 0.0f), zb = (z1v[r] != 0.0f);
      const float cn = zz ? ig : (zb ? (f * cold + ig) : cold);  // UPDATE/FLUSH/COPY
      const float th = o * tanhf(cn);
      const float hn = (zz || zb) ? th : h2old;
      w.c2[idx] = cn;
      w.h2m[idx] = hn;
      const f16 hi = (f16)hn;
      const f16 lo = (f16)((hn - (float)hi) * SC);
      const size_t off = (size_t)(b >> 4) * 16384 + (size_t)(jcol >> 5) * 512
                       + ((jcol >> 3) & 3) * 128 + (b & 15) * 8 + (jcol & 7);
      w.H2[pc][off] = hi;
      w.H2[pc][off + 8192] = lo;
      w.Z[pc][off]        = zb ? hi : (f16)0.f;  // z1_new * h2_new for next step1
      w.Z[pc][off + 8192] = zb ? lo : (f16)0.f;
    }
  } else {
    // z2 logit (fp64): s = (h2@U11_2)_z + z1n*(h1n@W01_2)_z + bias
    const int b = tid;
    const f16* pa = w.H2[pp] + (size_t)(b >> 4) * 16384 + (b & 15) * 8;
    const f16* pb = w.H1[pc] + (size_t)(b >> 4) * 16384 + (b & 15) * 8;
    double da[2] = {0.0, 0.0}, db[2] = {0.0, 0.0};
#pragma unroll 4
    for (int ks = 0; ks < 16; ++ks) {
#pragma unroll
      for (int qq = 0; qq < 4; ++qq) {
        const int j = ks * 32 + qq * 8;
        f16x8 h8  = ldf(pa + ks * 512 + qq * 128);
        f16x8 l8  = ldf(pa + ks * 512 + qq * 128 + 8192);
        f16x8 h8b = ldf(pb + ks * 512 + qq * 128);
        f16x8 l8b = ldf(pb + ks * 512 + qq * 128 + 8192);
#pragma unroll
        for (int i = 0; i < 8; ++i) {
          double ha = (double)(float)h8[i]  + (double)(float)l8[i]  * (1.0 / 2048.0);
          double hb = (double)(float)h8b[i] + (double)(float)l8b[i] * (1.0 / 2048.0);
          da[i & 1] += ha * (double)w.wz2[j + i];
          db[i & 1] += hb * (double)w.wz2[1024 + j + i];
        }
      }
    }
    const double z1n = (double)w.z1[pc][b];
    double s = (da[0] + da[1]) + z1n * (db[0] + db[1]) + (double)w.b2f[2048];
    float sz = (float)s;
    w.z2[pc][b] = (((sz + 1.0f) * 0.5f) > 0.5f) ? 1.0f : 0.0f;
  }
}

__global__ __launch_bounds__(256) void out_final(WS w, void* __restrict__ out)
{
  const int F32 = *w.flag;
  const int lane = threadIdx.x & 63, wv = threadIdx.x >> 6;
  out_tile(w, out, F32, 1, 511, blockIdx.x, wv, lane);  // parity of t=511 is 1
}

extern "C" void kernel_launch(void* const* d_in, const int* in_sizes, int n_in,
                              void* d_out, int out_size, void* d_ws, size_t ws_size,
                              hipStream_t stream)
{
  (void)in_sizes; (void)n_in; (void)out_size; (void)ws_size;
  const void* x     = d_in[0];
  const void* U11_1 = d_in[1];
  const void* U21_1 = d_in[2];
  const void* W01_1 = d_in[3];
  const void* bias1 = d_in[4];
  const void* U11_2 = d_in[5];
  const void* W01_2 = d_in[6];
  const void* bias2 = d_in[7];
  const void* l1W   = d_in[8];
  const void* l1b   = d_in[9];
  const void* l2W   = d_in[10];
  const void* l2b   = d_in[11];

  char* base = (char*)d_ws;
  size_t o = 0;
  auto take = [&](size_t bytes) -> char* {
    char* p = base + o;
    o = (o + bytes + 1023) & ~(size_t)1023;
    return p;
  };
  WS w;
  w.PB1aH = (f16*)take(1048576 * 2); w.PB1aL = (f16*)take(1048576 * 2);
  w.PB1bH = (f16*)take(1048576 * 2); w.PB1bL = (f16*)take(1048576 * 2);
  w.PB2aH = (f16*)take(1048576 * 2); w.PB2aL = (f16*)take(1048576 * 2);
  w.PB2bH = (f16*)take(1048576 * 2); w.PB2bL = (f16*)take(1048576 * 2);
  w.PB1xH = (f16*)take(131072 * 2);  w.PB1xL = (f16*)take(131072 * 2);
  w.PBo   = (f16*)take(65536 * 2);
  for (int i = 0; i < 2; ++i) w.H1[i] = (f16*)take(262144 * 2);
  for (int i = 0; i < 2; ++i) w.H2[i] = (f16*)take(262144 * 2);
  for (int i = 0; i < 2; ++i) w.Z[i]  = (f16*)take(262144 * 2);
  w.c1  = (float*)take(131072 * 4);
  w.c2  = (float*)take(131072 * 4);
  w.h2m = (float*)take(131072 * 4);
  w.wz1 = (float*)take(2112 * 4);
  w.wz2 = (float*)take(2048 * 4);
  w.b1f = (float*)take(2049 * 4);
  w.b2f = (float*)take(2049 * 4);
  w.bof = (float*)take(64 * 4);
  for (int i = 0; i < 2; ++i) w.z1[i] = (float*)take(256 * 4);
  for (int i = 0; i < 2; ++i) w.z2[i] = (float*)take(256 * 4);
  w.flag = (int*)take(4 * 4);
  // total ~21.5 MB of d_ws

  detect_kernel<<<1, 64, 0, stream>>>((const u16*)x, w.flag);
  pack_kernel<<<(NPACK + 255) / 256, 256, 0, stream>>>(
      U11_1, U21_1, W01_1, bias1, U11_2, W01_2, bias2, l1W, l1b, l2W, l2b, w);
  init_kernel<<<3074, 256, 0, stream>>>(w);
  for (int t = 0; t < 512; ++t) {
    step1<<<273, 256, 0, stream>>>(x, d_out, w, t);
    step2<<<257, 256, 0, stream>>>(w, t);
  }
  out_final<<<16, 256, 0, stream>>>(w, d_out);
}

// Round 7
// 22603.685 us; speedup vs baseline: 1.4971x; 1.4971x over previous
//
#include <hip/hip_runtime.h>

typedef unsigned short u16;
typedef unsigned int u32;
typedef _Float16 f16;
typedef __attribute__((ext_vector_type(8))) _Float16 f16x8;
typedef __attribute__((ext_vector_type(4))) float f32x4;

#define TT 512
#define DD 64
#define SC 2048.0f
#define ISC (1.0f / 2048.0f)

// Activation buffers (H1/H2/Z): f16 hi/lo-split pairs, MFMA-fragment layout:
// [mtile(16)][ks(32: 0-15 hi, 16-31 lo*2^11)][1KB frag]; frag elem
// (m=lane&15, k=quad*8+i) at quad*128 + m*8 + (k&7). Weight B-frags likewise
// split into H and L (L pre-scaled by 2^11; true value = H + L/2^11).
struct WS {
  f16 *PB1aH, *PB1aL, *PB1bH, *PB1bL, *PB1xH, *PB1xL;
  f16 *PB2aH, *PB2aL, *PB2bH, *PB2bL, *PBo;
  float *wz1, *wz2, *b1f, *b2f, *bof;
  f16 *H1[2], *H2[2], *Z[2];
  float *c1, *c2, *h2m;
  float *z1[2], *z2[2];
  int *flag;  // 1 = inputs are float32, 0 = inputs are bf16
};

__device__ __forceinline__ float bf2f(u16 u) { return __uint_as_float(((u32)u) << 16); }
__device__ __forceinline__ u16 f2bf(float f) {
  u32 u = __float_as_uint(f);
  u += 0x7fffu + ((u >> 16) & 1u);
  return (u16)(u >> 16);
}
// dtype-flexible scalar load of input element i
__device__ __forceinline__ float ldw(const void* p, size_t i, int f32) {
  return f32 ? ((const float*)p)[i] : bf2f(((const u16*)p)[i]);
}
__device__ __forceinline__ float sigm(float x) { return 1.0f / (1.0f + expf(-x)); }
__device__ __forceinline__ f16x8 ldf(const f16* p) { return *(const f16x8*)p; }

#define MFMA(a, b, c) __builtin_amdgcn_mfma_f32_16x16x32_f16(a, b, c, 0, 0, 0)

// ---------------- dtype detection ----------------
__global__ void detect_kernel(const u16* __restrict__ x, int* __restrict__ flag)
{
  int tid = threadIdx.x;  // 64 threads
  int cnt = 0;
  for (int i = tid; i < 8192; i += 64) {
    int e = (x[i] >> 7) & 0xFF;
    cnt += (e >= 0xC0 || (e != 0 && e < 0x30)) ? 1 : 0;
  }
#pragma unroll
  for (int off = 32; off; off >>= 1) cnt += __shfl_down(cnt, off);
  if (tid == 0) *flag = (cnt > 100) ? 1 : 0;
}

// ---------------- prologue: weight packing ----------------
__device__ __forceinline__ void packGate(const void* __restrict__ U,
                                         f16* __restrict__ dstH, f16* __restrict__ dstL,
                                         int g, int KS, int F32) {
  int lane = g & 63;
  int rest = g >> 6;
  int t2 = rest & 1; rest >>= 1;
  int ks = rest % KS;
  int J  = rest / KS;
  int q = lane >> 4, n = lane & 15;
  int j = J * 8 + (n & 7);
  int c = (t2 * 2 + (n >> 3)) * 512 + j;
  int kb = ks * 32 + q * 8;
  f16 vh[8], vl[8];
#pragma unroll
  for (int i = 0; i < 8; ++i) {
    float v = ldw(U, (size_t)(kb + i) * 2049 + c, F32);
    f16 h = (f16)v;
    vh[i] = h;
    vl[i] = (f16)((v - (float)h) * SC);
  }
  *(f16x8*)(dstH + (size_t)g * 8) = *(f16x8*)vh;
  *(f16x8*)(dstL + (size_t)g * 8) = *(f16x8*)vl;
}

#define NPACK (4 * 131072 + 16384 + 8192 + 2112 + 2048 + 2049 + 2049 + 64)

__global__ __launch_bounds__(256) void pack_kernel(
    const void* __restrict__ U11_1, const void* __restrict__ U21_1,
    const void* __restrict__ W01_1, const void* __restrict__ bias1,
    const void* __restrict__ U11_2, const void* __restrict__ W01_2,
    const void* __restrict__ bias2, const void* __restrict__ l1W,
    const void* __restrict__ l1b, const void* __restrict__ l2W,
    const void* __restrict__ l2b, WS w)
{
  const int F32 = *w.flag;
  int gid = blockIdx.x * 256 + threadIdx.x;
  const int NG = 131072;
  if (gid < NG) { packGate(U11_1, w.PB1aH, w.PB1aL, gid, 16, F32); return; }
  gid -= NG;
  if (gid < NG) { packGate(U21_1, w.PB1bH, w.PB1bL, gid, 16, F32); return; }
  gid -= NG;
  if (gid < NG) { packGate(U11_2, w.PB2aH, w.PB2aL, gid, 16, F32); return; }
  gid -= NG;
  if (gid < NG) { packGate(W01_2, w.PB2bH, w.PB2bL, gid, 16, F32); return; }
  gid -= NG;
  if (gid < 16384) { packGate(W01_1, w.PB1xH, w.PB1xL, gid, 2, F32); return; }
  gid -= 16384;
  if (gid < 8192) {  // PBo (hi only): [w4][ks 0..31][lane][8]
    int lane = gid & 63;
    int rest = gid >> 6;
    int ks = rest & 31;
    int w4 = rest >> 5;
    int q = lane >> 4;
    int d = w4 * 16 + (lane & 15);
    int kb = ks * 32 + q * 8;
    f16 v[8];
#pragma unroll
    for (int i = 0; i < 8; ++i) {
      int k = kb + i;
      float s = (k < 512) ? ldw(l1W, (size_t)d * 512 + k, F32)
                          : ldw(l2W, (size_t)d * 512 + (k - 512), F32);
      v[i] = (f16)s;
    }
    *(f16x8*)(w.PBo + (size_t)gid * 8) = *(f16x8*)v;
    return;
  }
  gid -= 8192;
  if (gid < 2112) {  // z-column weights, cell1 (fp32 exact)
    int i = gid; float s;
    if (i < 512)       s = ldw(U11_1, (size_t)i * 2049 + 2048, F32);
    else if (i < 1024) s = ldw(U11_1, (size_t)(i - 512) * 2049 + 2048, F32);
    else if (i < 1536) s = ldw(U21_1, (size_t)(i - 1024) * 2049 + 2048, F32);
    else if (i < 2048) s = ldw(U21_1, (size_t)(i - 1536) * 2049 + 2048, F32);
    else               s = ldw(W01_1, (size_t)(i - 2048) * 2049 + 2048, F32);
    w.wz1[i] = s; return;
  }
  gid -= 2112;
  if (gid < 2048) {  // z-column weights, cell2
    int i = gid; float s;
    if (i < 512)       s = ldw(U11_2, (size_t)i * 2049 + 2048, F32);
    else if (i < 1024) s = ldw(U11_2, (size_t)(i - 512) * 2049 + 2048, F32);
    else if (i < 1536) s = ldw(W01_2, (size_t)(i - 1024) * 2049 + 2048, F32);
    else               s = ldw(W01_2, (size_t)(i - 1536) * 2049 + 2048, F32);
    w.wz2[i] = s; return;
  }
  gid -= 2048;
  if (gid < 2049) { w.b1f[gid] = ldw(bias1, gid, F32); return; }
  gid -= 2049;
  if (gid < 2049) { w.b2f[gid] = ldw(bias2, gid, F32); return; }
  gid -= 2049;
  if (gid < 64) { w.bof[gid] = ldw(l1b, gid, F32) + ldw(l2b, gid, F32); return; }
}

__global__ __launch_bounds__(256) void init_kernel(WS w)
{
  size_t id = (size_t)blockIdx.x * 256 + threadIdx.x;
  const size_t nw = 131072;  // u32 words per f16 state buffer
  if (id < 3 * nw) {
    u32* p = (id < nw) ? (u32*)w.H1[1] : (id < 2 * nw) ? (u32*)w.H2[1] : (u32*)w.Z[1];
    p[id % nw] = 0u;
    return;
  }
  id -= 3 * nw;
  const size_t nf = 131072;
  if (id < 3 * nf) {
    float* p = (id < nf) ? w.c1 : (id < 2 * nf) ? w.c2 : w.h2m;
    p[id % nf] = 0.0f;
    return;
  }
  id -= 3 * nf;
  if (id < 512) {
    ((id < 256) ? w.z1[1] : w.z2[1])[id & 255] = 0.0f;
  }
}

// ---------------- output tile: out[b,twrite,:] = h1@l1W^T + h2@l2W^T + bias ----
__device__ __forceinline__ void out_tile(const WS& w, void* __restrict__ out, int F32,
                                         int pq, int twrite, int ot, int wv, int lane)
{
  const f16* A1 = w.H1[pq] + (size_t)ot * 16384 + lane * 8;  // hi sections only
  const f16* A2 = w.H2[pq] + (size_t)ot * 16384 + lane * 8;
  const f16* Bo = w.PBo + (size_t)wv * 16384 + lane * 8;
  f32x4 acc = {0.f, 0.f, 0.f, 0.f};
#pragma unroll
  for (int k = 0; k < 16; ++k) acc = MFMA(ldf(A1 + k * 512), ldf(Bo + k * 512), acc);
#pragma unroll
  for (int k = 0; k < 16; ++k) acc = MFMA(ldf(A2 + k * 512), ldf(Bo + (16 + k) * 512), acc);
  const int q = lane >> 4;
  const int d = wv * 16 + (lane & 15);
  const float bias = w.bof[d];
#pragma unroll
  for (int r = 0; r < 4; ++r) {
    const int b = ot * 16 + q * 4 + r;
    const size_t idx = ((size_t)b * TT + twrite) * DD + d;
    const float val = acc[r] + bias;
    if (F32) ((float*)out)[idx] = val;
    else     ((u16*)out)[idx] = f2bf(val);
  }
}

// ---------------- step1: cell 1 (GEMM + gates + z1) + out_{t-1} ----------------
__global__ __launch_bounds__(256) void step1(const void* __restrict__ x,
                                             void* __restrict__ out, WS w, int t)
{
  __shared__ double red1[256];
  const int F32 = *w.flag;
  const int pc = t & 1, pp = pc ^ 1;
  const int bid = blockIdx.x;
  const int tid = threadIdx.x;
  const int lane = tid & 63, wv = tid >> 6;

  if (bid < 256) {
    const int mt = bid >> 5, Jp = bid & 31;
    const int mhalf = wv & 1, cp = wv >> 1;
    const int J = Jp * 2 + cp;
    const int mtile = mt * 2 + mhalf;
    const int m0 = mtile * 16;
    const f16* A1 = w.H1[pp] + (size_t)mtile * 16384 + lane * 8;
    const f16* AZ = w.Z[pp]  + (size_t)mtile * 16384 + lane * 8;
    const f16* BaH = w.PB1aH + (size_t)J * 16384 + lane * 8;
    const f16* BaL = w.PB1aL + (size_t)J * 16384 + lane * 8;
    const f16* BbH = w.PB1bH + (size_t)J * 16384 + lane * 8;
    const f16* BbL = w.PB1bL + (size_t)J * 16384 + lane * 8;
    const f16* BxH = w.PB1xH + (size_t)J * 2048  + lane * 8;
    const f16* BxL = w.PB1xL + (size_t)J * 2048  + lane * 8;
    f32x4 hFI = {0.f,0.f,0.f,0.f}, lFI = {0.f,0.f,0.f,0.f};
    f32x4 hOG = {0.f,0.f,0.f,0.f}, lOG = {0.f,0.f,0.f,0.f};
#pragma unroll
    for (int k = 0; k < 16; ++k) {  // h1 @ U11_1, full hi/lo product (3 terms)
      f16x8 ah = ldf(A1 + k * 512);
      f16x8 al = ldf(A1 + (16 + k) * 512);
      f16x8 b0h = ldf(BaH + k * 1024), b0l = ldf(BaL + k * 1024);
      f16x8 b1h = ldf(BaH + k * 1024 + 512), b1l = ldf(BaL + k * 1024 + 512);
      hFI = MFMA(ah, b0h, hFI);
      lFI = MFMA(al, b0h, lFI); lFI = MFMA(ah, b0l, lFI);
      hOG = MFMA(ah, b1h, hOG);
      lOG = MFMA(al, b1h, lOG); lOG = MFMA(ah, b1l, lOG);
    }
#pragma unroll
    for (int k = 0; k < 16; ++k) {  // (z1_prev * h2) @ U21_1
      f16x8 ah = ldf(AZ + k * 512);
      f16x8 al = ldf(AZ + (16 + k) * 512);
      f16x8 b0h = ldf(BbH + k * 1024), b0l = ldf(BbL + k * 1024);
      f16x8 b1h = ldf(BbH + k * 1024 + 512), b1l = ldf(BbL + k * 1024 + 512);
      hFI = MFMA(ah, b0h, hFI);
      lFI = MFMA(al, b0h, lFI); lFI = MFMA(ah, b0l, lFI);
      hOG = MFMA(ah, b1h, hOG);
      lOG = MFMA(al, b1h, lOG); lOG = MFMA(ah, b1l, lOG);
    }
    {  // x_t @ W01_1 with hi/lo split of x
      const int row = m0 + (lane & 15);
      const int qq = lane >> 4;
#pragma unroll
      for (int kx = 0; kx < 2; ++kx) {
        const int d = kx * 32 + qq * 8;
        const size_t xoff = ((size_t)row * TT + t) * DD + d;
        float xv[8];
        if (F32) {
          const float* px = (const float*)x + xoff;
          float4 r0 = *(const float4*)px;
          float4 r1 = *(const float4*)(px + 4);
          xv[0]=r0.x; xv[1]=r0.y; xv[2]=r0.z; xv[3]=r0.w;
          xv[4]=r1.x; xv[5]=r1.y; xv[6]=r1.z; xv[7]=r1.w;
        } else {
          const u16* px = (const u16*)x + xoff;
          uint4 raw = *(const uint4*)px;
          u32 rr4[4] = {raw.x, raw.y, raw.z, raw.w};
#pragma unroll
          for (int i = 0; i < 4; ++i) {
            xv[2*i]   = bf2f((u16)(rr4[i] & 0xffffu));
            xv[2*i+1] = bf2f((u16)(rr4[i] >> 16));
          }
        }
        f16x8 axh, axl;
#pragma unroll
        for (int i = 0; i < 8; ++i) {
          f16 h = (f16)xv[i];
          axh[i] = h;
          axl[i] = (f16)((xv[i] - (float)h) * SC);
        }
        f16x8 b0h = ldf(BxH + kx * 1024), b0l = ldf(BxL + kx * 1024);
        f16x8 b1h = ldf(BxH + kx * 1024 + 512), b1l = ldf(BxL + kx * 1024 + 512);
        hFI = MFMA(axh, b0h, hFI);
        lFI = MFMA(axl, b0h, lFI); lFI = MFMA(axh, b0l, lFI);
        hOG = MFMA(axh, b1h, hOG);
        lOG = MFMA(axl, b1h, lOG); lOG = MFMA(axh, b1l, lOG);
      }
    }
    float accFI[4], accOG[4];
#pragma unroll
    for (int r = 0; r < 4; ++r) {
      accFI[r] = hFI[r] + lFI[r] * ISC;
      accOG[r] = hOG[r] + lOG[r] * ISC;
    }
    // fused cell-1 epilogue (z = z1_prev, z_bottom = 1 -> h = o*tanh(c))
    const int q = lane >> 4;
    const int jcol = J * 8 + (lane & 7);
    const bool ilane = (lane & 8) != 0;
    float oFI[4], oOG[4];
#pragma unroll
    for (int r = 0; r < 4; ++r) {
      oFI[r] = __shfl_xor(accFI[r], 8);
      oOG[r] = __shfl_xor(accOG[r], 8);
    }
    const float bf_ = w.b1f[jcol], bi_ = w.b1f[512 + jcol];
    const float bo_ = w.b1f[1024 + jcol], bg_ = w.b1f[1536 + jcol];
    const int r0 = ilane ? 2 : 0;
#pragma unroll
    for (int rr = 0; rr < 2; ++rr) {
      const int r = r0 + rr;
      const int b = m0 + q * 4 + r;
      const float sf = (ilane ? oFI[r] : accFI[r]) + bf_;
      const float si = (ilane ? accFI[r] : oFI[r]) + bi_;
      const float so = (ilane ? oOG[r] : accOG[r]) + bo_;
      const float sg = (ilane ? accOG[r] : oOG[r]) + bg_;
      const float f = sigm(sf), i_ = sigm(si), o = sigm(so), g = tanhf(sg);
      const int idx = b * 512 + jcol;
      const float cold = w.c1[idx];
      const float z1p = w.z1[pp][b];
      const float ig = i_ * g;
      const float cn = (z1p != 0.0f) ? ig : (f * cold + ig);
      const float hn = o * tanhf(cn);
      w.c1[idx] = cn;
      const f16 hi = (f16)hn;
      const f16 lo = (f16)((hn - (float)hi) * SC);
      const size_t off = (size_t)(b >> 4) * 16384 + (size_t)(jcol >> 5) * 512
                       + ((jcol >> 3) & 3) * 128 + (b & 15) * 8 + (jcol & 7);
      w.H1[pc][off] = hi;
      w.H1[pc][off + 8192] = lo;
    }
  } else if (bid < 320) {
    // z1 logit: one WAVE per batch row; lane (ks,qq) covers an 8-elem group.
    // Reduction via LDS + serial fp64 sum (no 64-bit shuffles).
    const int b = (bid - 256) * 4 + wv;
    const int ks = lane >> 2;   // 0..15
    const int qq = lane & 3;    // 0..3
    const size_t fro = (size_t)(b >> 4) * 16384 + (b & 15) * 8
                     + (size_t)ks * 512 + (size_t)qq * 128;
    const f16* pa = w.H1[pp] + fro;
    const f16* pz = w.Z[pp]  + fro;
    const int j = ks * 32 + qq * 8;
    f16x8 h8 = ldf(pa), l8 = ldf(pa + 8192);
    f16x8 h8z = ldf(pz), l8z = ldf(pz + 8192);
    double acc = 0.0;
#pragma unroll
    for (int i = 0; i < 8; ++i) {
      double ha = (double)(float)h8[i]  + (double)(float)l8[i]  * (1.0 / 2048.0);
      double hz = (double)(float)h8z[i] + (double)(float)l8z[i] * (1.0 / 2048.0);
      acc += ha * (double)w.wz1[j + i];
      acc += hz * (double)w.wz1[1024 + j + i];
    }
    {  // x part: lane d = lane handles one element
      float xv = ldw(x, ((size_t)b * TT + t) * DD + lane, F32);
      acc += (double)xv * (double)w.wz1[2048 + lane];
    }
    red1[tid] = acc;
    __syncthreads();
    if (lane == 0) {
      double s = (double)w.b1f[2048];
      for (int i = 0; i < 64; ++i) s += red1[wv * 64 + i];
      float sz = (float)s;
      float zh = (sz + 1.0f) * 0.5f;  // round-half-even(zh) == (zh > 0.5)
      w.z1[pc][b] = (zh > 0.5f) ? 1.0f : 0.0f;
    }
  } else {
    if (t == 0) return;  // out_{t-1} piggyback
    out_tile(w, out, F32, pp, t - 1, bid - 320, wv, lane);
  }
}

// ---------------- step2: cell 2 (GEMM + gates + z2) ----------------
__global__ __launch_bounds__(256) void step2(WS w, int t)
{
  __shared__ double redA[256];
  __shared__ double redB[256];
  const int pc = t & 1, pp = pc ^ 1;
  const int bid = blockIdx.x;
  const int tid = threadIdx.x;
  const int lane = tid & 63, wv = tid >> 6;
  if (bid < 256) {
    const int mt = bid >> 5, Jp = bid & 31;
    const int mhalf = wv & 1, cp = wv >> 1;
    const int J = Jp * 2 + cp;
    const int mtile = mt * 2 + mhalf;
    const int m0 = mtile * 16;
    const f16* Aa = w.H2[pp] + (size_t)mtile * 16384 + lane * 8;  // h2_prev
    const f16* Ab = w.H1[pc] + (size_t)mtile * 16384 + lane * 8;  // h1_new
    const f16* BaH = w.PB2aH + (size_t)J * 16384 + lane * 8;
    const f16* BaL = w.PB2aL + (size_t)J * 16384 + lane * 8;
    const f16* BbH = w.PB2bH + (size_t)J * 16384 + lane * 8;
    const f16* BbL = w.PB2bL + (size_t)J * 16384 + lane * 8;
    f32x4 aFIh = {0.f,0.f,0.f,0.f}, aFIl = {0.f,0.f,0.f,0.f};
    f32x4 aOGh = {0.f,0.f,0.f,0.f}, aOGl = {0.f,0.f,0.f,0.f};
    f32x4 bFIh = {0.f,0.f,0.f,0.f}, bFIl = {0.f,0.f,0.f,0.f};
    f32x4 bOGh = {0.f,0.f,0.f,0.f}, bOGl = {0.f,0.f,0.f,0.f};
#pragma unroll
    for (int k = 0; k < 16; ++k) {  // h2 @ U11_2
      f16x8 ah = ldf(Aa + k * 512);
      f16x8 al = ldf(Aa + (16 + k) * 512);
      f16x8 b0h = ldf(BaH + k * 1024), b0l = ldf(BaL + k * 1024);
      f16x8 b1h = ldf(BaH + k * 1024 + 512), b1l = ldf(BaL + k * 1024 + 512);
      aFIh = MFMA(ah, b0h, aFIh);
      aFIl = MFMA(al, b0h, aFIl); aFIl = MFMA(ah, b0l, aFIl);
      aOGh = MFMA(ah, b1h, aOGh);
      aOGl = MFMA(al, b1h, aOGl); aOGl = MFMA(ah, b1l, aOGl);
    }
#pragma unroll
    for (int k = 0; k < 16; ++k) {  // h1_new @ W01_2 (z1-scaled in epilogue)
      f16x8 ah = ldf(Ab + k * 512);
      f16x8 al = ldf(Ab + (16 + k) * 512);
      f16x8 b0h = ldf(BbH + k * 1024), b0l = ldf(BbL + k * 1024);
      f16x8 b1h = ldf(BbH + k * 1024 + 512), b1l = ldf(BbL + k * 1024 + 512);
      bFIh = MFMA(ah, b0h, bFIh);
      bFIl = MFMA(al, b0h, bFIl); bFIl = MFMA(ah, b0l, bFIl);
      bOGh = MFMA(ah, b1h, bOGh);
      bOGl = MFMA(al, b1h, bOGl); bOGl = MFMA(ah, b1l, bOGl);
    }
    const int q = lane >> 4;
    const int jcol = J * 8 + (lane & 7);
    const bool ilane = (lane & 8) != 0;
    float z1v[4], z2v[4], cFI[4], cOG[4];
#pragma unroll
    for (int r = 0; r < 4; ++r) {
      const int b = m0 + q * 4 + r;
      z1v[r] = w.z1[pc][b];
      z2v[r] = w.z2[pp][b];
      const float av = aFIh[r] + aFIl[r] * ISC;
      const float bv = bFIh[r] + bFIl[r] * ISC;
      const float av2 = aOGh[r] + aOGl[r] * ISC;
      const float bv2 = bOGh[r] + bOGl[r] * ISC;
      cFI[r] = av + z1v[r] * bv;
      cOG[r] = av2 + z1v[r] * bv2;
    }
    float oFI[4], oOG[4];
#pragma unroll
    for (int r = 0; r < 4; ++r) {
      oFI[r] = __shfl_xor(cFI[r], 8);
      oOG[r] = __shfl_xor(cOG[r], 8);
    }
    const float bf_ = w.b2f[jcol], bi_ = w.b2f[512 + jcol];
    const float bo_ = w.b2f[1024 + jcol], bg_ = w.b2f[1536 + jcol];
    const int r0 = ilane ? 2 : 0;
#pragma unroll
    for (int rr = 0; rr < 2; ++rr) {
      const int r = r0 + rr;
      const int b = m0 + q * 4 + r;
      const float sf = (ilane ? oFI[r] : cFI[r]) + bf_;
      const float si = (ilane ? cFI[r] : oFI[r]) + bi_;
      const float so = (ilane ? oOG[r] : cOG[r]) + bo_;
      const float sg = (ilane ? cOG[r] : oOG[r]) + bg_;
      const float f = sigm(sf), i_ = sigm(si), o = sigm(so), g = tanhf(sg);
      const int idx = b * 512 + jcol;
      const float cold = w.c2[idx];
      const float h2old = w.h2m[idx];
      const float ig = i_ * g;
      const bool zz = (z2v[r] != 0.0f), zb = (z1v[r] != 0.0f);
      const float cn = zz ? ig : (zb ? (f * cold + ig) : cold);  // UPDATE/FLUSH/COPY
      const float th = o * tanhf(cn);
      const float hn = (zz || zb) ? th : h2old;
      w.c2[idx] = cn;
      w.h2m[idx] = hn;
      const f16 hi = (f16)hn;
      const f16 lo = (f16)((hn - (float)hi) * SC);
      const size_t off = (size_t)(b >> 4) * 16384 + (size_t)(jcol >> 5) * 512
                       + ((jcol >> 3) & 3) * 128 + (b & 15) * 8 + (jcol & 7);
      w.H2[pc][off] = hi;
      w.H2[pc][off + 8192] = lo;
      w.Z[pc][off]        = zb ? hi : (f16)0.f;  // z1_new * h2_new for next step1
      w.Z[pc][off + 8192] = zb ? lo : (f16)0.f;
    }
  } else {
    // z2 logit: one WAVE per batch row; s = (h2@U)_z + z1n*(h1n@W)_z + bias.
    // Reduction via LDS + serial fp64 sum (no 64-bit shuffles).
    const int b = (bid - 256) * 4 + wv;
    const int ks = lane >> 2;
    const int qq = lane & 3;
    const size_t fro = (size_t)(b >> 4) * 16384 + (b & 15) * 8
                     + (size_t)ks * 512 + (size_t)qq * 128;
    const f16* pa = w.H2[pp] + fro;
    const f16* pb = w.H1[pc] + fro;
    const int j = ks * 32 + qq * 8;
    f16x8 h8  = ldf(pa), l8  = ldf(pa + 8192);
    f16x8 h8b = ldf(pb), l8b = ldf(pb + 8192);
    double da = 0.0, db = 0.0;
#pragma unroll
    for (int i = 0; i < 8; ++i) {
      double ha = (double)(float)h8[i]  + (double)(float)l8[i]  * (1.0 / 2048.0);
      double hb = (double)(float)h8b[i] + (double)(float)l8b[i] * (1.0 / 2048.0);
      da += ha * (double)w.wz2[j + i];
      db += hb * (double)w.wz2[1024 + j + i];
    }
    redA[tid] = da;
    redB[tid] = db;
    __syncthreads();
    if (lane == 0) {
      double sa = 0.0, sb = 0.0;
      for (int i = 0; i < 64; ++i) { sa += redA[wv * 64 + i]; sb += redB[wv * 64 + i]; }
      const double z1n = (double)w.z1[pc][b];
      double s = sa + z1n * sb + (double)w.b2f[2048];
      float sz = (float)s;
      w.z2[pc][b] = (((sz + 1.0f) * 0.5f) > 0.5f) ? 1.0f : 0.0f;
    }
  }
}

__global__ __launch_bounds__(256) void out_final(WS w, void* __restrict__ out)
{
  const int F32 = *w.flag;
  const int lane = threadIdx.x & 63, wv = threadIdx.x >> 6;
  out_tile(w, out, F32, 1, 511, blockIdx.x, wv, lane);  // parity of t=511 is 1
}

extern "C" void kernel_launch(void* const* d_in, const int* in_sizes, int n_in,
                              void* d_out, int out_size, void* d_ws, size_t ws_size,
                              hipStream_t stream)
{
  (void)in_sizes; (void)n_in; (void)out_size; (void)ws_size;
  const void* x     = d_in[0];
  const void* U11_1 = d_in[1];
  const void* U21_1 = d_in[2];
  const void* W01_1 = d_in[3];
  const void* bias1 = d_in[4];
  const void* U11_2 = d_in[5];
  const void* W01_2 = d_in[6];
  const void* bias2 = d_in[7];
  const void* l1W   = d_in[8];
  const void* l1b   = d_in[9];
  const void* l2W   = d_in[10];
  const void* l2b   = d_in[11];

  char* base = (char*)d_ws;
  size_t o = 0;
  auto take = [&](size_t bytes) -> char* {
    char* p = base + o;
    o = (o + bytes + 1023) & ~(size_t)1023;
    return p;
  };
  WS w;
  w.PB1aH = (f16*)take(1048576 * 2); w.PB1aL = (f16*)take(1048576 * 2);
  w.PB1bH = (f16*)take(1048576 * 2); w.PB1bL = (f16*)take(1048576 * 2);
  w.PB2aH = (f16*)take(1048576 * 2); w.PB2aL = (f16*)take(1048576 * 2);
  w.PB2bH = (f16*)take(1048576 * 2); w.PB2bL = (f16*)take(1048576 * 2);
  w.PB1xH = (f16*)take(131072 * 2);  w.PB1xL = (f16*)take(131072 * 2);
  w.PBo   = (f16*)take(65536 * 2);
  for (int i = 0; i < 2; ++i) w.H1[i] = (f16*)take(262144 * 2);
  for (int i = 0; i < 2; ++i) w.H2[i] = (f16*)take(262144 * 2);
  for (int i = 0; i < 2; ++i) w.Z[i]  = (f16*)take(262144 * 2);
  w.c1  = (float*)take(131072 * 4);
  w.c2  = (float*)take(131072 * 4);
  w.h2m = (float*)take(131072 * 4);
  w.wz1 = (float*)take(2112 * 4);
  w.wz2 = (float*)take(2048 * 4);
  w.b1f = (float*)take(2049 * 4);
  w.b2f = (float*)take(2049 * 4);
  w.bof = (float*)take(64 * 4);
  for (int i = 0; i < 2; ++i) w.z1[i] = (float*)take(256 * 4);
  for (int i = 0; i < 2; ++i) w.z2[i] = (float*)take(256 * 4);
  w.flag = (int*)take(4 * 4);
  // total ~21.5 MB of d_ws

  detect_kernel<<<1, 64, 0, stream>>>((const u16*)x, w.flag);
  pack_kernel<<<(NPACK + 255) / 256, 256, 0, stream>>>(
      U11_1, U21_1, W01_1, bias1, U11_2, W01_2, bias2, l1W, l1b, l2W, l2b, w);
  init_kernel<<<3074, 256, 0, stream>>>(w);
  for (int t = 0; t < 512; ++t) {
    step1<<<336, 256, 0, stream>>>(x, d_out, w, t);
    step2<<<320, 256, 0, stream>>>(w, t);
  }
  out_final<<<16, 256, 0, stream>>>(w, d_out);
}